// Round 1
// baseline (582.914 us; speedup 1.0000x reference)
//
#include <hip/hip_runtime.h>

// DifferentiableNLMS v3: B=32, T=2000, F=513, L=32.
// Same P=2 compute core as v2 (513 waves, 2 lanes/problem, dpp pair traffic).
// Change: X/Y prefetch moved from a 32-deep REGISTER pipeline (which the
// allocator collapsed at VGPR=68, exposing memory latency every step) to
// LDS staging via fire-and-forget global_load_lds:
//   - double-buffered 16-step tiles, 16 gl_lds instrs per tile
//     (lanes 0-31 stage step t, lanes 32-63 stage t+1 -> 2 steps/instr)
//   - counted s_waitcnt vmcnt(32) at tile boundaries: waits only for the
//     tile about to be consumed; next tile's burst + last tile's E-stores
//     stay in flight (never drain to 0 in the main loop)
//   - per-step x/y come from conflict-free ds_read (pairs broadcast).
// Register state drops to W[16]+w[16]+tile regs; no long-lived load dests.

#define LF   32
#define TT   2000
#define FF   513
#define BB   32
#define STEPSZ 0.1f
#define EPSV   1e-8f
#define NT   16              // time steps per LDS tile (== window slots)
#define NTILES (TT / NT)     // 125

__device__ __forceinline__ float dpp_swap1(float v) {
    // quad_perm [1,0,3,2]: exchange with lane^1
    return __int_as_float(
        __builtin_amdgcn_mov_dpp(__float_as_int(v), 0xB1, 0xF, 0xF, true));
}

__device__ __forceinline__ void gload_lds(const float* g, float* l) {
    // 4B per lane; LDS dest = uniform base + lane*4 (linear, matches layout).
    __builtin_amdgcn_global_load_lds(
        (const __attribute__((address_space(1))) void*)g,
        (__attribute__((address_space(3))) void*)l, 4, 0, 0);
}

__global__ __launch_bounds__(64, 1)
void nlms_kernel(const float* __restrict__ X, const float* __restrict__ Y,
                 const float* __restrict__ Wp, float* __restrict__ E,
                 float* __restrict__ Wout) {
    __shared__ float xb[2][NT][32];
    __shared__ float yb[2][NT][32];

    const int lane = threadIdx.x;            // 0..63, all lanes live
    const int half = lane & 1;               // 0: taps 0-15, 1: taps 16-31
    const int prob = blockIdx.x * 32 + (lane >> 1);   // 513*32 = 16416 exact
    const int b = prob / FF;
    const int f = prob - b * FF;

    // Staging mapping: column = lane&31 (one per problem), lane>>5 = +0/+1 step.
    const int ps = blockIdx.x * 32 + (lane & 31);
    const int bs = ps / FF;
    const int fs = ps - bs * FF;
    const float* Xs = X + (size_t)bs * TT * FF + (size_t)(lane >> 5) * FF + fs;
    const float* Ys = Y + (size_t)bs * TT * FF + (size_t)(lane >> 5) * FF + fs;

    float*    Ec   = E + (size_t)b * TT * FF + f;
    const int colW = b * (LF * FF) + (16 * half) * FF + f;

    float W[16];
#pragma unroll
    for (int i = 0; i < 16; ++i) W[i] = Wp[colW + i * FF];

    // Circular window: slot (k & 15) gets step k's incoming element.
    // Lane h's window = X[k-31+16h .. k-16+16h], zero-init for k<0 history.
    float w[16];
#pragma unroll
    for (int i = 0; i < 16; ++i) w[i] = 0.0f;

    float s = 0.0f;   // this lane's window sum-of-squares (incremental)

    // Prologue: stage tiles 0 and 1 (32 outstanding loads, no dest regs).
#pragma unroll
    for (int q = 0; q < NT / 2; ++q)
        gload_lds(Xs + (size_t)(2 * q) * FF, &xb[0][2 * q][0]);
#pragma unroll
    for (int q = 0; q < NT / 2; ++q)
        gload_lds(Ys + (size_t)(2 * q) * FF, &yb[0][2 * q][0]);
#pragma unroll
    for (int q = 0; q < NT / 2; ++q)
        gload_lds(Xs + (size_t)(NT + 2 * q) * FF, &xb[1][2 * q][0]);
#pragma unroll
    for (int q = 0; q < NT / 2; ++q)
        gload_lds(Ys + (size_t)(NT + 2 * q) * FF, &yb[1][2 * q][0]);

#pragma unroll 1
    for (int tt = 0; tt < NTILES; ++tt) {
        // Counted waits. Event order (steady state) oldest->newest:
        //   burst(tt) | stores(tile tt-1) x16 | burst(tt+1) x16
        // vmcnt(32) retires burst(tt) and older; keeps the newest 32
        // (prev tile's stores + next tile's burst) in flight.
        // Tiles 0 and NTILES-1 have only 16 newer events -> vmcnt(16).
        if (tt == 0 || tt == NTILES - 1)
            asm volatile("s_waitcnt vmcnt(16)" ::: "memory");
        else
            asm volatile("s_waitcnt vmcnt(32)" ::: "memory");

        const int buf = tt & 1;
        const int p   = lane >> 1;

        // Pull the tile into registers; compiler schedules fine-grained
        // lgkmcnt between these conflict-free ds_reads and first uses.
        float xs[NT], ys[NT];
#pragma unroll
        for (int i = 0; i < NT; ++i) {
            xs[i] = xb[buf][i][p];
            ys[i] = yb[buf][i][p];
        }

#pragma unroll
        for (int j = 0; j < NT; ++j) {
            const float x_new = xs[j];
            const float y     = ys[j];

            // Window slide: drop oldest, insert incoming.
            const float out = w[j];           // X[k-32+16h]
            const float sh  = dpp_swap1(out); // partner's expiring element
            const float inc = half ? x_new    // lane1 inserts X[k]
                                   : sh;      // lane0 inherits X[k-16]
            w[j] = inc;

            // Incremental sum of squares of this lane's window.
            s = fmaf(inc, inc, s);
            s = fmaf(-out, out, s);

            // Partial dot: tap i (local) reads slot (j+1+i)&15.
            float a0 = 0.f, a1 = 0.f, a2 = 0.f, a3 = 0.f;
#pragma unroll
            for (int i = 0; i < 16; i += 4) {
                a0 = fmaf(W[i + 0], w[(j + 1 + i + 0) & 15], a0);
                a1 = fmaf(W[i + 1], w[(j + 1 + i + 1) & 15], a1);
                a2 = fmaf(W[i + 2], w[(j + 1 + i + 2) & 15], a2);
                a3 = fmaf(W[i + 3], w[(j + 1 + i + 3) & 15], a3);
            }
            const float part = (a0 + a1) + (a2 + a3);

            // Pair reductions (both lanes end up with full sums).
            const float yh  = part + dpp_swap1(part);
            const float nrm = s + dpp_swap1(s);

            const float e = y - yh;
            const float d = nrm + EPSV;
            float r = __builtin_amdgcn_rcpf(d);
            r = r * fmaf(-d, r, 2.0f);        // 1 NR step
            const float c = (STEPSZ * e) * r;

#pragma unroll
            for (int i = 0; i < 16; ++i)
                W[i] = fmaf(c, w[(j + 1 + i) & 15], W[i]);

            if (half == 0) Ec[(tt * NT + j) * FF] = e;   // e same in both lanes
        }

        // Refill the buffer we just consumed with tile tt+2.
        if (tt + 2 < NTILES) {
            // Ensure this buffer's ds_reads fully drained before overwrite;
            // also fences gl_lds issue below the E-stores above (vmcnt order).
            asm volatile("s_waitcnt lgkmcnt(0)" ::: "memory");
            const size_t t0 = (size_t)(tt + 2) * NT;
#pragma unroll
            for (int q = 0; q < NT / 2; ++q)
                gload_lds(Xs + (t0 + 2 * q) * FF, &xb[buf][2 * q][0]);
#pragma unroll
            for (int q = 0; q < NT / 2; ++q)
                gload_lds(Ys + (t0 + 2 * q) * FF, &yb[buf][2 * q][0]);
        }
    }

#pragma unroll
    for (int i = 0; i < 16; ++i) Wout[colW + i * FF] = W[i];
}

extern "C" void kernel_launch(void* const* d_in, const int* in_sizes, int n_in,
                              void* d_out, int out_size, void* d_ws, size_t ws_size,
                              hipStream_t stream) {
    const float* X  = (const float*)d_in[0];   // X_hat_mag (B,T,F)
    const float* Y  = (const float*)d_in[1];   // Y_mag     (B,T,F)
    const float* Wp = (const float*)d_in[2];   // W_prev    (B,L,F)
    float* E    = (float*)d_out;               // (B,T,F)
    float* Wout = E + (size_t)BB * TT * FF;    // (B,L,F)

    // 513 blocks x 64 threads: 513 waves, 32 problems each, zero remainder.
    nlms_kernel<<<dim3(513), dim3(64), 0, stream>>>(X, Y, Wp, E, Wout);
}

// Round 2
// 523.985 us; speedup vs baseline: 1.1125x; 1.1125x over previous
//
#include <hip/hip_runtime.h>

// DifferentiableNLMS v4: B=32, T=2000, F=513, L=32.
// Same P=2 compute core as v2/v3 (513 waves, 2 lanes/problem, dpp pair ops).
// v2/v3 post-mortem: allocator squeezed to 64-68 VGPRs and SANK the x/y
// prefetch (register array in v2, LDS reads in v3) to per-step dependent
// loads -> ~2x120-200cy exposed latency every step (473 cy/step measured,
// VALU issue only ~116). Fix: feed machinery in VOLATILE INLINE ASM the
// scheduler cannot sink:
//   - gl_lds stages 16-step x/y tiles, double-buffered (as v3)
//   - explicit 4-step ds_read register pipeline (xp[4]/yp[4]) via volatile
//     asm ds_read_b32; volatile ordering guarantees the 4-step distance
//   - counted s_waitcnt lgkmcnt(6) before consumption (retires exactly the
//     oldest x/y pair) + sched_barrier(0) (rule: hipcc hoists VALU past
//     asm waitcnt otherwise)
//   - single counted vmcnt(12) per tile at j==12 (retires next tile's
//     16-load burst; keeps 12 newest E-stores in flight; never drains)

#define LF   32
#define TT   2000
#define FF   513
#define BB   32
#define STEPSZ 0.1f
#define EPSV   1e-8f
#define NT   16              // time steps per LDS tile
#define NTILES (TT / NT)     // 125
#define PD   4               // ds_read pipeline depth (steps)

__device__ __forceinline__ float dpp_swap1(float v) {
    // quad_perm [1,0,3,2]: exchange with lane^1
    return __int_as_float(
        __builtin_amdgcn_mov_dpp(__float_as_int(v), 0xB1, 0xF, 0xF, true));
}

__device__ __forceinline__ void gload_lds(const float* g, float* l) {
    // 4B per lane; LDS dest = uniform base + lane*4 (linear, matches layout).
    __builtin_amdgcn_global_load_lds(
        (const __attribute__((address_space(1))) void*)g,
        (__attribute__((address_space(3))) void*)l, 4, 0, 0);
}

__global__ __launch_bounds__(64, 1)
void nlms_kernel(const float* __restrict__ X, const float* __restrict__ Y,
                 const float* __restrict__ Wp, float* __restrict__ E,
                 float* __restrict__ Wout) {
    // [buf][x=0/y=1][slot][prob]: buf stride 4096B, y-offset 2048B,
    // slot stride 128B. gl_lds writes rows of 32 floats linearly.
    __shared__ float sb[2][2][NT][32];

    const int lane = threadIdx.x;            // 0..63, all lanes live
    const int half = lane & 1;               // 0: taps 0-15, 1: taps 16-31
    const int prob = blockIdx.x * 32 + (lane >> 1);   // 513*32 = 16416 exact
    const int b = prob / FF;
    const int f = prob - b * FF;

    // Staging mapping: column = lane&31 (one per problem), lane>>5 = +0/+1 step.
    const int ps = blockIdx.x * 32 + (lane & 31);
    const int bs = ps / FF;
    const int fs = ps - bs * FF;
    const float* Xs = X + (size_t)bs * TT * FF + (size_t)(lane >> 5) * FF + fs;
    const float* Ys = Y + (size_t)bs * TT * FF + (size_t)(lane >> 5) * FF + fs;

    float*    Ec   = E + (size_t)b * TT * FF + f;
    const int colW = b * (LF * FF) + (16 * half) * FF + f;

    float W[16];
#pragma unroll
    for (int i = 0; i < 16; ++i) W[i] = Wp[colW + i * FF];

    float w[16];
#pragma unroll
    for (int i = 0; i < 16; ++i) w[i] = 0.0f;

    float s = 0.0f;   // this lane's window sum-of-squares (incremental)

    // LDS byte address of this lane's column in buffer 0 / buffer 1.
    const int p = lane >> 1;
    const uint32_t base = (uint32_t)(uintptr_t)
        (__attribute__((address_space(3))) void*)&sb[0][0][0][0];
    const uint32_t a0 = base + (uint32_t)(p * 4);
    const uint32_t a1 = a0 + 4096u;

    // Prologue: stage tiles 0 and 1 (32 gl_lds, no dest regs).
#pragma unroll
    for (int q = 0; q < NT / 2; ++q)
        gload_lds(Xs + (size_t)(2 * q) * FF, &sb[0][0][2 * q][0]);
#pragma unroll
    for (int q = 0; q < NT / 2; ++q)
        gload_lds(Ys + (size_t)(2 * q) * FF, &sb[0][1][2 * q][0]);
#pragma unroll
    for (int q = 0; q < NT / 2; ++q)
        gload_lds(Xs + (size_t)(NT + 2 * q) * FF, &sb[1][0][2 * q][0]);
#pragma unroll
    for (int q = 0; q < NT / 2; ++q)
        gload_lds(Ys + (size_t)(NT + 2 * q) * FF, &sb[1][1][2 * q][0]);

    // Tile 0 readable (burst 1 still in flight).
    asm volatile("s_waitcnt vmcnt(16)" ::: "memory");

    // Prime the 4-step ds_read register pipeline (steps 0..3, buffer 0).
    float xp[PD], yp[PD];
#pragma unroll
    for (int i = 0; i < PD; ++i) {
        asm volatile("ds_read_b32 %0, %1"
                     : "=v"(xp[i]) : "v"(a0 + 128u * i));
        asm volatile("ds_read_b32 %0, %1"
                     : "=v"(yp[i]) : "v"(a0 + 2048u + 128u * i));
    }

#pragma unroll 1
    for (int tt = 0; tt < NTILES; ++tt) {
        const uint32_t acur = (tt & 1) ? a1 : a0;
        const uint32_t anxt = (tt & 1) ? a0 : a1;

#pragma unroll
        for (int j = 0; j < NT; ++j) {
            if (j == 12) {
                // Retire next tile's 16-load burst before its first ds_reads
                // (issued at j=12..15). 12 newest events = this tile's
                // E-stores (1/step, j=0..11) stay in flight. Never drain.
                asm volatile("s_waitcnt vmcnt(12)" ::: "memory");
            }

            // Wait for the oldest in-flight x/y pair (ours): 3 newer pairs
            // outstanding -> lgkmcnt(6). Then fence: hipcc otherwise hoists
            // the consuming FMAs above an asm waitcnt (register-only ops).
            asm volatile("s_waitcnt lgkmcnt(6)" ::: "memory");
            __builtin_amdgcn_sched_barrier(0);

            const float x_new = xp[j & (PD - 1)];
            const float y     = yp[j & (PD - 1)];

            // Issue reads for step j+PD (volatile: cannot be sunk).
            {
                const int jn = j + PD;
                const uint32_t ax = (jn < NT) ? (acur + 128u * jn)
                                              : (anxt + 128u * (jn - NT));
                asm volatile("ds_read_b32 %0, %1"
                             : "=v"(xp[j & (PD - 1)]) : "v"(ax));
                asm volatile("ds_read_b32 %0, %1"
                             : "=v"(yp[j & (PD - 1)]) : "v"(ax + 2048u));
            }

            // ---- compute body: identical to v2/v3 ----
            const float out = w[j];           // X[k-32+16h]
            const float sh  = dpp_swap1(out); // partner's expiring element
            const float inc = half ? x_new    // lane1 inserts X[k]
                                   : sh;      // lane0 inherits X[k-16]
            w[j] = inc;

            s = fmaf(inc, inc, s);
            s = fmaf(-out, out, s);

            float a0v = 0.f, a1v = 0.f, a2v = 0.f, a3v = 0.f;
#pragma unroll
            for (int i = 0; i < 16; i += 4) {
                a0v = fmaf(W[i + 0], w[(j + 1 + i + 0) & 15], a0v);
                a1v = fmaf(W[i + 1], w[(j + 1 + i + 1) & 15], a1v);
                a2v = fmaf(W[i + 2], w[(j + 1 + i + 2) & 15], a2v);
                a3v = fmaf(W[i + 3], w[(j + 1 + i + 3) & 15], a3v);
            }
            const float part = (a0v + a1v) + (a2v + a3v);

            const float yh  = part + dpp_swap1(part);
            const float nrm = s + dpp_swap1(s);

            const float e = y - yh;
            const float d = nrm + EPSV;
            float r = __builtin_amdgcn_rcpf(d);
            r = r * fmaf(-d, r, 2.0f);        // 1 NR step
            const float c = (STEPSZ * e) * r;

#pragma unroll
            for (int i = 0; i < 16; ++i)
                W[i] = fmaf(c, w[(j + 1 + i) & 15], W[i]);

            if (half == 0) Ec[(tt * NT + j) * FF] = e;   // e same in both lanes
        }

        // Refill the buffer just consumed with tile tt+2. Outstanding
        // ds_reads at this point all target the OTHER buffer (steps
        // tt*16+16..19), so no lgkm wait is needed before overwrite.
        if (tt + 2 < NTILES) {
            const size_t t0 = (size_t)(tt + 2) * NT;
            float (*xb)[32] = sb[tt & 1][0];
            float (*yb)[32] = sb[tt & 1][1];
#pragma unroll
            for (int q = 0; q < NT / 2; ++q)
                gload_lds(Xs + (t0 + 2 * q) * FF, &xb[2 * q][0]);
#pragma unroll
            for (int q = 0; q < NT / 2; ++q)
                gload_lds(Ys + (t0 + 2 * q) * FF, &yb[2 * q][0]);
        }
    }

#pragma unroll
    for (int i = 0; i < 16; ++i) Wout[colW + i * FF] = W[i];
}

extern "C" void kernel_launch(void* const* d_in, const int* in_sizes, int n_in,
                              void* d_out, int out_size, void* d_ws, size_t ws_size,
                              hipStream_t stream) {
    const float* X  = (const float*)d_in[0];   // X_hat_mag (B,T,F)
    const float* Y  = (const float*)d_in[1];   // Y_mag     (B,T,F)
    const float* Wp = (const float*)d_in[2];   // W_prev    (B,L,F)
    float* E    = (float*)d_out;               // (B,T,F)
    float* Wout = E + (size_t)BB * TT * FF;    // (B,L,F)

    // 513 blocks x 64 threads: 513 waves, 32 problems each, zero remainder.
    nlms_kernel<<<dim3(513), dim3(64), 0, stream>>>(X, Y, Wp, E, Wout);
}